// Round 8
// baseline (212.436 us; speedup 1.0000x reference)
//
#include <hip/hip_runtime.h>
#include <hip/hip_bf16.h>

#define NODES 2048
#define DIM   64
#define K_TOP 30
#define BATCH 16
#define BN    (NODES * BATCH)
#define NEGINF (-3.402823466e38f)
#define EPS 1e-5f
#define TBC 128    // cos GEMM tile (128x128 per block)
#define KPAD 132   // 128 + 4 floats: keeps every AsT[k] row 16B-aligned for b128

// ---------------------------------------------------------------------------
// DPP wave64 reduction helpers (rocPRIM pattern: row_shr 1/2/4/8 +
// row_bcast15 + row_bcast31, result in lane 63, broadcast via readlane).
// ---------------------------------------------------------------------------
template <int CTRL>
__device__ __forceinline__ float dpp_add_f32(float x) {
    int y = __builtin_amdgcn_update_dpp(0, __float_as_int(x), CTRL, 0xf, 0xf, true);
    return x + __int_as_float(y);
}

__device__ __forceinline__ float wave_sum(float x) {
    x = dpp_add_f32<0x111>(x);
    x = dpp_add_f32<0x112>(x);
    x = dpp_add_f32<0x114>(x);
    x = dpp_add_f32<0x118>(x);
    x = dpp_add_f32<0x142>(x);
    x = dpp_add_f32<0x143>(x);
    return __int_as_float(__builtin_amdgcn_readlane(__float_as_int(x), 63));
}

template <int CTRL>
__device__ __forceinline__ float dpp_max_f32(float x) {
    int y = __builtin_amdgcn_update_dpp(__float_as_int(x), __float_as_int(x),
                                        CTRL, 0xf, 0xf, false);
    return fmaxf(x, __int_as_float(y));
}

__device__ __forceinline__ float wave_max(float x) {
    x = dpp_max_f32<0x111>(x);
    x = dpp_max_f32<0x112>(x);
    x = dpp_max_f32<0x114>(x);
    x = dpp_max_f32<0x118>(x);
    x = dpp_max_f32<0x142>(x);
    x = dpp_max_f32<0x143>(x);
    return __int_as_float(__builtin_amdgcn_readlane(__float_as_int(x), 63));
}

// lexicographic (value desc, index asc) argmax step on a (bv,bj) pair
#define ARGMAX_STEP(CTRL)                                                       \
    do {                                                                        \
        int nv_ = __builtin_amdgcn_update_dpp(__float_as_int(bv),               \
                      __float_as_int(bv), (CTRL), 0xf, 0xf, false);             \
        int nj_ = __builtin_amdgcn_update_dpp(bj, bj, (CTRL), 0xf, 0xf, false); \
        float nvf_ = __int_as_float(nv_);                                       \
        bool g_ = (nvf_ > bv) || (nvf_ == bv && nj_ < bj);                      \
        bv = g_ ? nvf_ : bv;                                                    \
        bj = g_ ? nj_ : bj;                                                     \
    } while (0)

// ---------------------------------------------------------------------------
// K1: normalized embedding  wn = w / ||w||_row   (one wave per row)
// ---------------------------------------------------------------------------
__global__ __launch_bounds__(256) void normalize_kernel(const float* __restrict__ w,
                                                        float* __restrict__ wn) {
    int r = blockIdx.x * 4 + (threadIdx.x >> 6);
    int lane = threadIdx.x & 63;
    float v = w[r * DIM + lane];
    float s = wave_sum(v * v);
    wn[r * DIM + lane] = v * rsqrtf(s);
}

// ---------------------------------------------------------------------------
// K2: cos = wn @ wn^T. 128x128 tile, 512 thr, 8x4 acc/thread.
// k-TRANSPOSED LDS (AsT[k][r], pad +4 floats) so per k-step each thread does
// 3x ds_read_b128 (8 A-rows + 4 B-cols) for 32 FMAs — 1.5 B/FMA vs the old
// 2 B/FMA of scalar b32 reads (which made the 64-tile version LDS-bound
// ~20 µs). Staging writes take a one-time 8-way bank conflict (~540 cyc).
// k ascends per accumulator -> bit-identical to the previous version.
// ---------------------------------------------------------------------------
__global__ __launch_bounds__(512) void cos_kernel(const float* __restrict__ wn,
                                                  float* __restrict__ cosm) {
    __shared__ float AsT[DIM][KPAD];
    __shared__ float BsT[DIM][KPAD];
    const int tid = threadIdx.x;
    const int bi = blockIdx.x, bj = blockIdx.y;

    #pragma unroll
    for (int it = 0; it < 16; ++it) {
        int s = it * 512 + tid;            // wave-uniform r, lane = d: coalesced
        int r = s >> 6, d = s & 63;
        AsT[d][r] = wn[(bi * TBC + r) * DIM + d];
        BsT[d][r] = wn[(bj * TBC + r) * DIM + d];
    }
    __syncthreads();

    const int ti = tid >> 5;   // 0..15 -> rows ti*8 .. ti*8+7
    const int tj = tid & 31;   // 0..31 -> cols tj*4 .. tj*4+3
    float acc[8][4] = {};
    #pragma unroll 4
    for (int k = 0; k < DIM; ++k) {
        float4 a0 = *(const float4*)&AsT[k][ti * 8];      // 16B-aligned (KPAD=132)
        float4 a1 = *(const float4*)&AsT[k][ti * 8 + 4];
        float4 b0 = *(const float4*)&BsT[k][tj * 4];
        float a[8] = {a0.x, a0.y, a0.z, a0.w, a1.x, a1.y, a1.z, a1.w};
        float b[4] = {b0.x, b0.y, b0.z, b0.w};
        #pragma unroll
        for (int u = 0; u < 8; ++u)
            #pragma unroll
            for (int v = 0; v < 4; ++v)
                acc[u][v] = fmaf(a[u], b[v], acc[u][v]);
    }
    #pragma unroll
    for (int u = 0; u < 8; ++u) {
        float4 o = make_float4(acc[u][0], acc[u][1], acc[u][2], acc[u][3]);
        *(float4*)&cosm[(size_t)(bi * TBC + ti * 8 + u) * NODES + bj * TBC + tj * 4] = o;
    }
}

// ---------------------------------------------------------------------------
// K3: top-30 per row. One wave per row; coalesced row load into 32 regs/lane.
// Per extraction: TREE local argmax (depth 5; fold upper half onto lower so
// lower q wins exact ties — identical winners to the serial scan) + DPP
// butterfly + scalar-branch removal. Tie-break matches lax.top_k (lower idx).
// ---------------------------------------------------------------------------
__global__ __launch_bounds__(256) void topk_kernel(const float* __restrict__ cosm,
                                                   int* __restrict__ topk) {
    const int i = blockIdx.x * 4 + (threadIdx.x >> 6);
    const int lane = threadIdx.x & 63;
    const float* row = cosm + (size_t)i * NODES;

    float v[NODES / 64];
    #pragma unroll
    for (int q = 0; q < NODES / 64; ++q) v[q] = row[q * 64 + lane];  // 256B/inst

    int res = 0;
    for (int t = 0; t < K_TOP; ++t) {
        // depth-5 tree argmax over 32 regs; all indices static after unroll
        float tv[16]; int tq[16];
        #pragma unroll
        for (int u = 0; u < 16; ++u) {
            bool g = v[2 * u + 1] > v[2 * u];     // strict: tie keeps lower q
            tv[u] = g ? v[2 * u + 1] : v[2 * u];
            tq[u] = g ? (2 * u + 1) : (2 * u);
        }
        #pragma unroll
        for (int h = 8; h >= 1; h >>= 1) {
            #pragma unroll
            for (int u = 0; u < h; ++u) {
                bool g = tv[u + h] > tv[u];       // tq[u] < tq[u+h] always
                tv[u] = g ? tv[u + h] : tv[u];
                tq[u] = g ? tq[u + h] : tq[u];
            }
        }
        float bv = tv[0];
        int bj = tq[0] * 64 + lane;
        // wave argmax via DPP (ties -> lower j)
        ARGMAX_STEP(0x111);
        ARGMAX_STEP(0x112);
        ARGMAX_STEP(0x114);
        ARGMAX_STEP(0x118);
        ARGMAX_STEP(0x142);
        ARGMAX_STEP(0x143);
        const int wj = __builtin_amdgcn_readlane(bj, 63);   // SGPR-uniform
        res = (lane == t) ? wj : res;
        const int wl = wj & 63;
        const int wq = wj >> 6;
        #pragma unroll
        for (int q = 0; q < NODES / 64; ++q)
            if (q == wq && lane == wl) v[q] = NEGINF;  // q==wq: scalar branch
    }
    if (lane < K_TOP) topk[i * K_TOP + lane] = res;
}

// ---------------------------------------------------------------------------
// K4: xl = x @ lin_w ; a_i/a_j per node (fused). One wave per output row.
// ---------------------------------------------------------------------------
__global__ __launch_bounds__(256) void lin_kernel(const float* __restrict__ x,
                                                  const float* __restrict__ lin_w,
                                                  const float* __restrict__ emb,
                                                  const float* __restrict__ att_i,
                                                  const float* __restrict__ att_j,
                                                  const float* __restrict__ att_em_i,
                                                  const float* __restrict__ att_em_j,
                                                  float* __restrict__ xl,
                                                  float* __restrict__ ai,
                                                  float* __restrict__ aj) {
    __shared__ float lw[DIM * DIM];   // 16 KiB
    __shared__ float xs[16 * DIM];    // 4 KiB
    const int tid = threadIdx.x;
    const int wave = tid >> 6;
    const int lane = tid & 63;
    const int row0 = blockIdx.x * 16;

    for (int t = tid; t < DIM * DIM; t += 256) lw[t] = lin_w[t];
    for (int t = tid; t < 16 * DIM; t += 256) xs[t] = x[row0 * DIM + t];
    __syncthreads();

    for (int rr = wave; rr < 16; rr += 4) {
        const int r = row0 + rr;
        float acc = 0.f;
        #pragma unroll
        for (int f = 0; f < DIM; ++f)
            acc = fmaf(xs[rr * DIM + f], lw[f * DIM + lane], acc);  // stride-64: 2/bank = free
        xl[r * DIM + lane] = acc;

        const int i = r & (NODES - 1);
        const float em = emb[i * DIM + lane];
        float ti = wave_sum(acc * att_i[lane] + em * att_em_i[lane]);
        float tj = wave_sum(acc * att_j[lane] + em * att_em_j[lane]);
        if (lane == 0) { ai[r] = ti; aj[r] = tj; }
    }
}

// ---------------------------------------------------------------------------
// K5: per-node fused GAT aggregate + BN1 + ReLU + emb-mul + BN2 + ReLU + readout
// one 64-lane wave per target node; lane == feature dim.
// ---------------------------------------------------------------------------
__global__ __launch_bounds__(256) void agg_kernel(const int* __restrict__ topk,
                                                  const float* __restrict__ xl,
                                                  const float* __restrict__ ai,
                                                  const float* __restrict__ aj,
                                                  const float* __restrict__ emb,
                                                  const float* __restrict__ gnn_bias,
                                                  const float* __restrict__ g1, const float* __restrict__ b1,
                                                  const float* __restrict__ m1, const float* __restrict__ v1,
                                                  const float* __restrict__ g2, const float* __restrict__ b2,
                                                  const float* __restrict__ m2, const float* __restrict__ v2,
                                                  const float* __restrict__ out_w,
                                                  const float* __restrict__ out_b,
                                                  float* __restrict__ y) {
    const int e = blockIdx.x * 4 + (threadIdx.x >> 6);
    const int lane = threadIdx.x & 63;
    const int i = e & (NODES - 1);
    const int b = e >> 11;

    const float a_ie = ai[e];
    int nbr = 0;
    float raw = NEGINF;
    if (lane < K_TOP) {
        nbr = (b << 11) + topk[i * K_TOP + lane];
        float r0 = a_ie + aj[nbr];
        raw = (r0 >= 0.f) ? r0 : 0.2f * r0;   // leaky_relu(0.2)
    }
    const float m = wave_max(raw);
    float p = (lane < K_TOP) ? __expf(raw - m) : 0.f;
    const float s = wave_sum(p);
    const float inv = 1.f / s;

    float acc = 0.f;
    #pragma unroll
    for (int k = 0; k < K_TOP; ++k) {
        const float pk = __int_as_float(__builtin_amdgcn_readlane(__float_as_int(p), k));
        const int nb = __builtin_amdgcn_readlane(nbr, k);   // SGPR -> uniform base
        acc = fmaf(pk, xl[nb * DIM + lane], acc);           // 256B coalesced gather
    }

    float o = acc * inv + gnn_bias[lane];
    o = (o - m1[lane]) * rsqrtf(v1[lane] + EPS) * g1[lane] + b1[lane];
    o = fmaxf(o, 0.f);
    float h = o * emb[i * DIM + lane];
    h = (h - m2[lane]) * rsqrtf(v2[lane] + EPS) * g2[lane] + b2[lane];
    h = fmaxf(h, 0.f);
    float t = wave_sum(h * out_w[lane]);
    if (lane == 0) y[e] = t + out_b[0];
}

// ---------------------------------------------------------------------------
extern "C" void kernel_launch(void* const* d_in, const int* in_sizes, int n_in,
                              void* d_out, int out_size, void* d_ws, size_t ws_size,
                              hipStream_t stream) {
    const float* data      = (const float*)d_in[0];
    // d_in[1] org_edge_index: unused (prior_graph dynamic top-k path)
    const float* emb       = (const float*)d_in[2];
    const float* lin_w     = (const float*)d_in[3];
    const float* att_i     = (const float*)d_in[4];
    const float* att_j     = (const float*)d_in[5];
    const float* att_em_i  = (const float*)d_in[6];
    const float* att_em_j  = (const float*)d_in[7];
    const float* gnn_bias  = (const float*)d_in[8];
    const float* bn1_gamma = (const float*)d_in[9];
    const float* bn1_beta  = (const float*)d_in[10];
    const float* bn1_mean  = (const float*)d_in[11];
    const float* bn1_var   = (const float*)d_in[12];
    const float* bn2_gamma = (const float*)d_in[13];
    const float* bn2_beta  = (const float*)d_in[14];
    const float* bn2_mean  = (const float*)d_in[15];
    const float* bn2_var   = (const float*)d_in[16];
    const float* out_w     = (const float*)d_in[17];
    const float* out_b     = (const float*)d_in[18];
    float* y = (float*)d_out;

    // workspace layout (bytes). cosm (16 MiB) is consumed by topk_kernel
    // BEFORE lin_kernel runs (same stream, serialized), so xl/ai/aj overlay it.
    char* ws = (char*)d_ws;
    float* cosm = (float*)(ws);                                  // 16 MiB (transient)
    float* xl   = (float*)(ws);                                  // 8 MiB, overlays cosm
    float* ai   = (float*)(ws + 8 * 1024 * 1024);                // 128 KiB
    float* aj   = (float*)(ws + 8 * 1024 * 1024 + 131072);       // 128 KiB
    float* wn   = (float*)(ws + 16 * 1024 * 1024);               // 512 KiB
    int*   topk = (int*)  (ws + 16 * 1024 * 1024 + 524288);      // 240 KiB

    normalize_kernel<<<NODES / 4, 256, 0, stream>>>(emb, wn);
    cos_kernel<<<dim3(NODES / TBC, NODES / TBC), 512, 0, stream>>>(wn, cosm);
    topk_kernel<<<NODES / 4, 256, 0, stream>>>(cosm, topk);
    lin_kernel<<<BN / 16, 256, 0, stream>>>(data, lin_w, emb, att_i, att_j,
                                            att_em_i, att_em_j, xl, ai, aj);
    agg_kernel<<<BN / 4, 256, 0, stream>>>(topk, xl, ai, aj, emb, gnn_bias,
                                           bn1_gamma, bn1_beta, bn1_mean, bn1_var,
                                           bn2_gamma, bn2_beta, bn2_mean, bn2_var,
                                           out_w, out_b, y);
}

// Round 9
// 172.967 us; speedup vs baseline: 1.2282x; 1.2282x over previous
//
#include <hip/hip_runtime.h>
#include <hip/hip_bf16.h>

#define NODES 2048
#define DIM   64
#define K_TOP 30
#define BATCH 16
#define BN    (NODES * BATCH)
#define NEGINF (-3.402823466e38f)
#define EPS 1e-5f
#define TBC 128    // cos GEMM tile (128x128 per block)
#define KPAD 132   // 128 + 4 floats: keeps every AsT[k] row 16B-aligned for b128

// ---------------------------------------------------------------------------
// DPP wave64 reduction helpers (rocPRIM pattern: row_shr 1/2/4/8 +
// row_bcast15 + row_bcast31, result in lane 63, broadcast via readlane).
// ---------------------------------------------------------------------------
template <int CTRL>
__device__ __forceinline__ float dpp_add_f32(float x) {
    int y = __builtin_amdgcn_update_dpp(0, __float_as_int(x), CTRL, 0xf, 0xf, true);
    return x + __int_as_float(y);
}

__device__ __forceinline__ float wave_sum(float x) {
    x = dpp_add_f32<0x111>(x);
    x = dpp_add_f32<0x112>(x);
    x = dpp_add_f32<0x114>(x);
    x = dpp_add_f32<0x118>(x);
    x = dpp_add_f32<0x142>(x);
    x = dpp_add_f32<0x143>(x);
    return __int_as_float(__builtin_amdgcn_readlane(__float_as_int(x), 63));
}

template <int CTRL>
__device__ __forceinline__ float dpp_max_f32(float x) {
    int y = __builtin_amdgcn_update_dpp(__float_as_int(x), __float_as_int(x),
                                        CTRL, 0xf, 0xf, false);
    return fmaxf(x, __int_as_float(y));
}

__device__ __forceinline__ float wave_max(float x) {
    x = dpp_max_f32<0x111>(x);
    x = dpp_max_f32<0x112>(x);
    x = dpp_max_f32<0x114>(x);
    x = dpp_max_f32<0x118>(x);
    x = dpp_max_f32<0x142>(x);
    x = dpp_max_f32<0x143>(x);
    return __int_as_float(__builtin_amdgcn_readlane(__float_as_int(x), 63));
}

// lexicographic (value desc, index asc) argmax step on a (bv,bj) pair
#define ARGMAX_STEP(CTRL)                                                       \
    do {                                                                        \
        int nv_ = __builtin_amdgcn_update_dpp(__float_as_int(bv),               \
                      __float_as_int(bv), (CTRL), 0xf, 0xf, false);             \
        int nj_ = __builtin_amdgcn_update_dpp(bj, bj, (CTRL), 0xf, 0xf, false); \
        float nvf_ = __int_as_float(nv_);                                       \
        bool g_ = (nvf_ > bv) || (nvf_ == bv && nj_ < bj);                      \
        bv = g_ ? nvf_ : bv;                                                    \
        bj = g_ ? nj_ : bj;                                                     \
    } while (0)

// ---------------------------------------------------------------------------
// K1: normalized embedding  wn = w / ||w||_row   (one wave per row)
// ---------------------------------------------------------------------------
__global__ __launch_bounds__(256) void normalize_kernel(const float* __restrict__ w,
                                                        float* __restrict__ wn) {
    int r = blockIdx.x * 4 + (threadIdx.x >> 6);
    int lane = threadIdx.x & 63;
    float v = w[r * DIM + lane];
    float s = wave_sum(v * v);
    wn[r * DIM + lane] = v * rsqrtf(s);
}

// ---------------------------------------------------------------------------
// K2: cos = wn @ wn^T. 128x128 tile, 512 thr, 8x4 acc/thread.
// k-TRANSPOSED LDS (AsT[k][r], pad +4 floats) -> 3x ds_read_b128 per k-step.
// ---------------------------------------------------------------------------
__global__ __launch_bounds__(512) void cos_kernel(const float* __restrict__ wn,
                                                  float* __restrict__ cosm) {
    __shared__ float AsT[DIM][KPAD];
    __shared__ float BsT[DIM][KPAD];
    const int tid = threadIdx.x;
    const int bi = blockIdx.x, bj = blockIdx.y;

    #pragma unroll
    for (int it = 0; it < 16; ++it) {
        int s = it * 512 + tid;            // wave-uniform r, lane = d: coalesced
        int r = s >> 6, d = s & 63;
        AsT[d][r] = wn[(bi * TBC + r) * DIM + d];
        BsT[d][r] = wn[(bj * TBC + r) * DIM + d];
    }
    __syncthreads();

    const int ti = tid >> 5;   // 0..15 -> rows ti*8 .. ti*8+7
    const int tj = tid & 31;   // 0..31 -> cols tj*4 .. tj*4+3
    float acc[8][4] = {};
    #pragma unroll 4
    for (int k = 0; k < DIM; ++k) {
        float4 a0 = *(const float4*)&AsT[k][ti * 8];      // 16B-aligned (KPAD=132)
        float4 a1 = *(const float4*)&AsT[k][ti * 8 + 4];
        float4 b0 = *(const float4*)&BsT[k][tj * 4];
        float a[8] = {a0.x, a0.y, a0.z, a0.w, a1.x, a1.y, a1.z, a1.w};
        float b[4] = {b0.x, b0.y, b0.z, b0.w};
        #pragma unroll
        for (int u = 0; u < 8; ++u)
            #pragma unroll
            for (int v = 0; v < 4; ++v)
                acc[u][v] = fmaf(a[u], b[v], acc[u][v]);
    }
    #pragma unroll
    for (int u = 0; u < 8; ++u) {
        float4 o = make_float4(acc[u][0], acc[u][1], acc[u][2], acc[u][3]);
        *(float4*)&cosm[(size_t)(bi * TBC + ti * 8 + u) * NODES + bj * TBC + tj * 4] = o;
    }
}

// ---------------------------------------------------------------------------
// K3: top-30 per row. One wave per row; coalesced row load into 32 regs/lane
// (serial-scan local argmax — R7-proven), DPP butterfly wave argmax, scalar
// removal. __launch_bounds__(256, 2): 2 waves/EU -> VGPR cap 256 so v[32]
// stays REGISTER-resident (default heuristic capped at ~64 VGPRs -> scratch,
// which was the 46-76 µs cost; grid is 2048 waves = 2/SIMD anyway).
// Tie-break: lower index wins (lax.top_k). Result order irrelevant downstream.
// ---------------------------------------------------------------------------
__global__ __launch_bounds__(256, 2) void topk_kernel(const float* __restrict__ cosm,
                                                      int* __restrict__ topk) {
    const int i = blockIdx.x * 4 + (threadIdx.x >> 6);
    const int lane = threadIdx.x & 63;
    const float* row = cosm + (size_t)i * NODES;

    float v[NODES / 64];
    #pragma unroll
    for (int q = 0; q < NODES / 64; ++q) v[q] = row[q * 64 + lane];  // 256B/inst

    int res = 0;
    for (int t = 0; t < K_TOP; ++t) {
        // lane-local serial argmax over 32 regs (lowest q on tie)
        float lm = v[0];
        int lq = 0;
        #pragma unroll
        for (int q = 1; q < NODES / 64; ++q) {
            bool g = v[q] > lm;
            lm = g ? v[q] : lm;
            lq = g ? q : lq;
        }
        float bv = lm;
        int bj = lq * 64 + lane;
        // wave argmax via DPP (ties -> lower j)
        ARGMAX_STEP(0x111);
        ARGMAX_STEP(0x112);
        ARGMAX_STEP(0x114);
        ARGMAX_STEP(0x118);
        ARGMAX_STEP(0x142);
        ARGMAX_STEP(0x143);
        const int wj = __builtin_amdgcn_readlane(bj, 63);   // SGPR-uniform
        res = (lane == t) ? wj : res;
        const int wl = wj & 63;
        const int wq = wj >> 6;
        #pragma unroll
        for (int q = 0; q < NODES / 64; ++q)
            if (q == wq && lane == wl) v[q] = NEGINF;  // q==wq: scalar branch
    }
    if (lane < K_TOP) topk[i * K_TOP + lane] = res;
}

// ---------------------------------------------------------------------------
// K4: xl = x @ lin_w ; a_i/a_j per node (fused). One wave per output row.
// ---------------------------------------------------------------------------
__global__ __launch_bounds__(256) void lin_kernel(const float* __restrict__ x,
                                                  const float* __restrict__ lin_w,
                                                  const float* __restrict__ emb,
                                                  const float* __restrict__ att_i,
                                                  const float* __restrict__ att_j,
                                                  const float* __restrict__ att_em_i,
                                                  const float* __restrict__ att_em_j,
                                                  float* __restrict__ xl,
                                                  float* __restrict__ ai,
                                                  float* __restrict__ aj) {
    __shared__ float lw[DIM * DIM];   // 16 KiB
    __shared__ float xs[16 * DIM];    // 4 KiB
    const int tid = threadIdx.x;
    const int wave = tid >> 6;
    const int lane = tid & 63;
    const int row0 = blockIdx.x * 16;

    for (int t = tid; t < DIM * DIM; t += 256) lw[t] = lin_w[t];
    for (int t = tid; t < 16 * DIM; t += 256) xs[t] = x[row0 * DIM + t];
    __syncthreads();

    for (int rr = wave; rr < 16; rr += 4) {
        const int r = row0 + rr;
        float acc = 0.f;
        #pragma unroll
        for (int f = 0; f < DIM; ++f)
            acc = fmaf(xs[rr * DIM + f], lw[f * DIM + lane], acc);  // stride-64: 2/bank = free
        xl[r * DIM + lane] = acc;

        const int i = r & (NODES - 1);
        const float em = emb[i * DIM + lane];
        float ti = wave_sum(acc * att_i[lane] + em * att_em_i[lane]);
        float tj = wave_sum(acc * att_j[lane] + em * att_em_j[lane]);
        if (lane == 0) { ai[r] = ti; aj[r] = tj; }
    }
}

// ---------------------------------------------------------------------------
// K5: per-node fused GAT aggregate + BN1 + ReLU + emb-mul + BN2 + ReLU + readout
// one 64-lane wave per target node; lane == feature dim.
// ---------------------------------------------------------------------------
__global__ __launch_bounds__(256) void agg_kernel(const int* __restrict__ topk,
                                                  const float* __restrict__ xl,
                                                  const float* __restrict__ ai,
                                                  const float* __restrict__ aj,
                                                  const float* __restrict__ emb,
                                                  const float* __restrict__ gnn_bias,
                                                  const float* __restrict__ g1, const float* __restrict__ b1,
                                                  const float* __restrict__ m1, const float* __restrict__ v1,
                                                  const float* __restrict__ g2, const float* __restrict__ b2,
                                                  const float* __restrict__ m2, const float* __restrict__ v2,
                                                  const float* __restrict__ out_w,
                                                  const float* __restrict__ out_b,
                                                  float* __restrict__ y) {
    const int e = blockIdx.x * 4 + (threadIdx.x >> 6);
    const int lane = threadIdx.x & 63;
    const int i = e & (NODES - 1);
    const int b = e >> 11;

    const float a_ie = ai[e];
    int nbr = 0;
    float raw = NEGINF;
    if (lane < K_TOP) {
        nbr = (b << 11) + topk[i * K_TOP + lane];
        float r0 = a_ie + aj[nbr];
        raw = (r0 >= 0.f) ? r0 : 0.2f * r0;   // leaky_relu(0.2)
    }
    const float m = wave_max(raw);
    float p = (lane < K_TOP) ? __expf(raw - m) : 0.f;
    const float s = wave_sum(p);
    const float inv = 1.f / s;

    float acc = 0.f;
    #pragma unroll
    for (int k = 0; k < K_TOP; ++k) {
        const float pk = __int_as_float(__builtin_amdgcn_readlane(__float_as_int(p), k));
        const int nb = __builtin_amdgcn_readlane(nbr, k);   // SGPR -> uniform base
        acc = fmaf(pk, xl[nb * DIM + lane], acc);           // 256B coalesced gather
    }

    float o = acc * inv + gnn_bias[lane];
    o = (o - m1[lane]) * rsqrtf(v1[lane] + EPS) * g1[lane] + b1[lane];
    o = fmaxf(o, 0.f);
    float h = o * emb[i * DIM + lane];
    h = (h - m2[lane]) * rsqrtf(v2[lane] + EPS) * g2[lane] + b2[lane];
    h = fmaxf(h, 0.f);
    float t = wave_sum(h * out_w[lane]);
    if (lane == 0) y[e] = t + out_b[0];
}

// ---------------------------------------------------------------------------
extern "C" void kernel_launch(void* const* d_in, const int* in_sizes, int n_in,
                              void* d_out, int out_size, void* d_ws, size_t ws_size,
                              hipStream_t stream) {
    const float* data      = (const float*)d_in[0];
    // d_in[1] org_edge_index: unused (prior_graph dynamic top-k path)
    const float* emb       = (const float*)d_in[2];
    const float* lin_w     = (const float*)d_in[3];
    const float* att_i     = (const float*)d_in[4];
    const float* att_j     = (const float*)d_in[5];
    const float* att_em_i  = (const float*)d_in[6];
    const float* att_em_j  = (const float*)d_in[7];
    const float* gnn_bias  = (const float*)d_in[8];
    const float* bn1_gamma = (const float*)d_in[9];
    const float* bn1_beta  = (const float*)d_in[10];
    const float* bn1_mean  = (const float*)d_in[11];
    const float* bn1_var   = (const float*)d_in[12];
    const float* bn2_gamma = (const float*)d_in[13];
    const float* bn2_beta  = (const float*)d_in[14];
    const float* bn2_mean  = (const float*)d_in[15];
    const float* bn2_var   = (const float*)d_in[16];
    const float* out_w     = (const float*)d_in[17];
    const float* out_b     = (const float*)d_in[18];
    float* y = (float*)d_out;

    // workspace layout (bytes). cosm (16 MiB) is consumed by topk_kernel
    // BEFORE lin_kernel runs (same stream, serialized), so xl/ai/aj overlay it.
    char* ws = (char*)d_ws;
    float* cosm = (float*)(ws);                                  // 16 MiB (transient)
    float* xl   = (float*)(ws);                                  // 8 MiB, overlays cosm
    float* ai   = (float*)(ws + 8 * 1024 * 1024);                // 128 KiB
    float* aj   = (float*)(ws + 8 * 1024 * 1024 + 131072);       // 128 KiB
    float* wn   = (float*)(ws + 16 * 1024 * 1024);               // 512 KiB
    int*   topk = (int*)  (ws + 16 * 1024 * 1024 + 524288);      // 240 KiB

    normalize_kernel<<<NODES / 4, 256, 0, stream>>>(emb, wn);
    cos_kernel<<<dim3(NODES / TBC, NODES / TBC), 512, 0, stream>>>(wn, cosm);
    topk_kernel<<<NODES / 4, 256, 0, stream>>>(cosm, topk);
    lin_kernel<<<BN / 16, 256, 0, stream>>>(data, lin_w, emb, att_i, att_j,
                                            att_em_i, att_em_j, xl, ai, aj);
    agg_kernel<<<BN / 4, 256, 0, stream>>>(topk, xl, ai, aj, emb, gnn_bias,
                                           bn1_gamma, bn1_beta, bn1_mean, bn1_var,
                                           bn2_gamma, bn2_beta, bn2_mean, bn2_var,
                                           out_w, out_b, y);
}